// Round 1
// 375.199 us; speedup vs baseline: 1.2797x; 1.2797x over previous
//
#include <hip/hip_runtime.h>
#include <cfloat>

#define HH 64
#define WW 64
#define NKEYS 17
#define CCH 32
#define BG_W 10.0f

__device__ inline void wave_argmin(float &v, int &i) {
    #pragma unroll
    for (int off = 32; off > 0; off >>= 1) {
        float ov = __shfl_down(v, off, 64);
        int   oi = __shfl_down(i, off, 64);
        if (ov < v || (ov == v && oi < i)) { v = ov; i = oi; }
    }
}

__global__ __launch_bounds__(256) void ee_kernel(
    const float* __restrict__ kq,      // (B, C, H, W)
    const float* __restrict__ mkeys,   // (B, N, C)
    const int*   __restrict__ mjoints, // (B, N, 2)
    float* __restrict__ out_joints,    // (B, N, 2) as float
    float* __restrict__ out_valid,     // (B, N) as float
    float* __restrict__ out_keys,      // (B, N, C)
    float* __restrict__ out_x4)        // (B, N, 256, 256)
{
    // XCD-aware swizzle: 1088 blocks = 8 XCDs * 136. Under the bid%8
    // round-robin dispatch heuristic, giving each XCD a CONTIGUOUS bn range
    // means each XCD touches only 8 b's of kq (8 * 512KB = 4MB = its L2),
    // instead of all XCDs re-fetching every b. Bijective since 1088%8==0.
    const int bid = blockIdx.x;
    const int bn  = (bid & 7) * (NKEYS * 8) + (bid >> 3);
    const int b   = bn / NKEYS;
    const int tid = threadIdx.x;

    __shared__ float s_mk[CCH];
    __shared__ __align__(16) float s_wd[HH * WW];
    __shared__ float s_rv[4];
    __shared__ int   s_ri[4];

    if (tid < CCH) s_mk[tid] = mkeys[bn * CCH + tid];
    __syncthreads();

    // uniform across block: k2 and nonzero flag
    float k2 = 0.0f;
    bool  nz = false;
    #pragma unroll
    for (int c = 0; c < CCH; c++) {
        float v = s_mk[c];
        k2 += v * v;
        nz = nz || (v != 0.0f);
    }

    const int kpx = mjoints[bn * 2 + 0];
    const int kpy = mjoints[bn * 2 + 1];
    // Border specials: when kp sits on a border col/row, that col/row is
    // written once at m=1 (reference's m<=m_left/right/up/down clamp logic).
    const int bxc = (kpx == 0) ? 0 : ((kpx == WW - 1) ? WW - 1 : -1);
    const int byc = (kpy == 0) ? 0 : ((kpy == HH - 1) ? HH - 1 : -1);

    const float4* kq4 = (const float4*)(kq + (size_t)b * CCH * HH * WW);

    float bestv = FLT_MAX;
    int   besti = 0;

    // ---- phase 1: weighted distance map into LDS + coarse argmin ----
    for (int j = 0; j < 4; j++) {
        const int chunk = tid + 256 * j;   // float4 chunk id, 0..1023
        float4 dot = make_float4(0.f, 0.f, 0.f, 0.f);
        float4 q2  = make_float4(0.f, 0.f, 0.f, 0.f);
        #pragma unroll
        for (int c = 0; c < CCH; c++) {
            float4 v = kq4[c * 1024 + chunk];
            float  m = s_mk[c];
            dot.x += v.x * m;  dot.y += v.y * m;
            dot.z += v.z * m;  dot.w += v.w * m;
            q2.x  += v.x * v.x; q2.y += v.y * v.y;
            q2.z  += v.z * v.z; q2.w += v.w * v.w;
        }
        float dots[4] = {dot.x, dot.y, dot.z, dot.w};
        float q2s[4]  = {q2.x,  q2.y,  q2.z,  q2.w};
        float4 wd;
        float* wdp = (float*)&wd;
        const int p0 = chunk * 4;
        #pragma unroll
        for (int k = 0; k < 4; k++) {
            const int p  = p0 + k;
            const int px = p & (WW - 1);
            const int py = p >> 6;
            float d2   = (q2s[k] + k2) - 2.0f * dots[k];
            float dist = sqrtf(fmaxf(d2, 0.0f));
            // Closed-form ring weight. The last (= max, since w grows with m)
            // move writing (px,py) is the Chebyshev ring index:
            //   col write at m=adx  iff ady<=adx<=15
            //   row write at m=ady  iff adx<=ady<=15
            //   border col/row write at m=1 iff on bxc/byc and other-|d|<=1
            const int adx = abs(px - kpx);
            const int ady = abs(py - kpy);
            int M = 0;
            if (adx <= 15 && ady <= adx) M = adx;
            if (ady <= 15 && adx <= ady) M = max(M, ady);
            if ((px == bxc && ady <= 1) || (py == byc && adx <= 1)) M = max(M, 1);
            float wgt = (M > 0) ? fmaf(0.25f, (float)M, 0.5f) : BG_W;
            float wv = dist * wgt;
            wdp[k] = wv;
            if (wv < bestv) { bestv = wv; besti = p; }   // p ascending per thread
        }
        ((float4*)s_wd)[chunk] = wd;
    }

    // ---- coarse block argmin (lexicographic: val, then lower index) ----
    __syncthreads();
    wave_argmin(bestv, besti);
    if ((tid & 63) == 0) { s_rv[tid >> 6] = bestv; s_ri[tid >> 6] = besti; }
    __syncthreads();
    if (tid == 0) {
        float v = s_rv[0]; int i0 = s_ri[0];
        for (int w2 = 1; w2 < 4; w2++) {
            float ov = s_rv[w2]; int oi = s_ri[w2];
            if (ov < v || (ov == v && oi < i0)) { v = ov; i0 = oi; }
        }
        s_rv[0] = v; s_ri[0] = i0;
    }
    __syncthreads();
    const float min_d = s_rv[0];
    const int   cbest = s_ri[0];
    const bool  valid = nz && ((int)floorf(min_d) <= 5);

    if (tid < CCH) {
        float o = valid ? kq[(size_t)(b * CCH + tid) * (HH * WW) + cbest] : s_mk[tid];
        out_keys[bn * CCH + tid] = o;
    }

    // ---- phase 2: 4x bilinear upsample, float4 stores ----
    // thread = (yg, jx): produces the 4 fine columns of coarse column jx
    // (fine x = 4jx..4jx+3) for fine rows [yg*64, yg*64+64).
    // Wave = one yg, lane = jx -> each row store is a contiguous 1KB.
    const int jx   = tid & 63;
    const int yg   = tid >> 6;
    const int jxm1 = max(jx - 1, 0);
    const int jxp1 = min(jx + 1, WW - 1);
    const bool xe0 = (jx == 0);        // fine cols 0,1: exact copy (jax edge norm)
    const bool xe1 = (jx == WW - 1);   // fine cols 254,255: exact copy

    // x-interp of coarse row cy into this thread's 4 fine columns
    auto xrow = [&](int cy) -> float4 {
        const float* rr = s_wd + cy * WW;
        const float a  = rr[jxm1];
        const float bb = rr[jx];
        const float c  = rr[jxp1];
        float4 o;
        o.x = xe0 ? bb : fmaf(0.375f, a, 0.625f * bb);
        o.y = xe0 ? bb : fmaf(0.125f, a, 0.875f * bb);
        o.z = xe1 ? bb : fmaf(0.125f, c, 0.875f * bb);
        o.w = xe1 ? bb : fmaf(0.375f, c, 0.625f * bb);
        return o;
    };
    auto lerp4 = [](float wa, const float4& A, float wb, const float4& B) {
        float4 o;
        o.x = fmaf(wa, A.x, wb * B.x);
        o.y = fmaf(wa, A.y, wb * B.y);
        o.z = fmaf(wa, A.z, wb * B.z);
        o.w = fmaf(wa, A.w, wb * B.w);
        return o;
    };

    float fbv = FLT_MAX;
    int   fbi = 0;
    auto upd = [&](float val, int idx) {
        if (val < fbv) { fbv = val; fbi = idx; }   // ascending idx -> first occurrence
    };

    float4* xo4 = (float4*)(out_x4 + (size_t)bn * (256 * 256)) + jx;

    const int jy0 = yg * 16;
    float4 Xc = xrow(jy0);
    float4 Xp = (jy0 > 0) ? xrow(jy0 - 1) : Xc;   // jy==0 handled by branch below

    for (int jy = jy0; jy < jy0 + 16; jy++) {
        const float4 Xn = (jy < HH - 1) ? xrow(jy + 1) : Xc;
        float4 v0, v1, v2, v3;
        if (jy == 0) { v0 = Xc; v1 = Xc; }
        else {
            v0 = lerp4(0.375f, Xp, 0.625f, Xc);
            v1 = lerp4(0.125f, Xp, 0.875f, Xc);
        }
        if (jy == HH - 1) { v2 = Xc; v3 = Xc; }
        else {
            v2 = lerp4(0.875f, Xc, 0.125f, Xn);
            v3 = lerp4(0.625f, Xc, 0.375f, Xn);
        }
        const int r0 = jy * 4;
        xo4[(size_t)(r0 + 0) * 64] = v0;
        xo4[(size_t)(r0 + 1) * 64] = v1;
        xo4[(size_t)(r0 + 2) * 64] = v2;
        xo4[(size_t)(r0 + 3) * 64] = v3;
        const int ib = r0 * 256 + 4 * jx;
        upd(v0.x, ib);       upd(v0.y, ib + 1);   upd(v0.z, ib + 2);   upd(v0.w, ib + 3);
        upd(v1.x, ib + 256); upd(v1.y, ib + 257); upd(v1.z, ib + 258); upd(v1.w, ib + 259);
        upd(v2.x, ib + 512); upd(v2.y, ib + 513); upd(v2.z, ib + 514); upd(v2.w, ib + 515);
        upd(v3.x, ib + 768); upd(v3.y, ib + 769); upd(v3.z, ib + 770); upd(v3.w, ib + 771);
        Xp = Xc;
        Xc = Xn;
    }

    // ---- fine block argmin + scalar outputs ----
    wave_argmin(fbv, fbi);
    __syncthreads();   // protect s_rv/s_ri reuse
    if ((tid & 63) == 0) { s_rv[tid >> 6] = fbv; s_ri[tid >> 6] = fbi; }
    __syncthreads();
    if (tid == 0) {
        float v = s_rv[0]; int i0 = s_ri[0];
        for (int w2 = 1; w2 < 4; w2++) {
            float ov = s_rv[w2]; int oi = s_ri[w2];
            if (ov < v || (ov == v && oi < i0)) { v = ov; i0 = oi; }
        }
        int sv, sh;
        if (valid) { sv = i0 >> 8; sh = i0 & 255; }
        else       { sv = -1;      sh = -1;       }
        out_joints[bn * 2 + 0] = (float)sv;
        out_joints[bn * 2 + 1] = (float)sh;
        out_valid[bn] = valid ? 1.0f : 0.0f;
    }
}

extern "C" void kernel_launch(void* const* d_in, const int* in_sizes, int n_in,
                              void* d_out, int out_size, void* d_ws, size_t ws_size,
                              hipStream_t stream) {
    const float* kq = (const float*)d_in[0];
    const float* mk = (const float*)d_in[1];
    const int*   mj = (const int*)d_in[2];

    const int B = in_sizes[1] / (NKEYS * CCH);   // 64
    const int BN = B * NKEYS;                    // 1088

    float* out_f     = (float*)d_out;
    float* o_joints  = out_f;                    // B*N*2
    float* o_valid   = o_joints + BN * 2;        // B*N
    float* o_keys    = o_valid + BN;             // B*N*C
    float* o_x4      = o_keys + BN * CCH;        // B*N*256*256

    ee_kernel<<<dim3(BN), dim3(256), 0, stream>>>(kq, mk, mj, o_joints, o_valid, o_keys, o_x4);
}

// Round 2
// 344.728 us; speedup vs baseline: 1.3929x; 1.0884x over previous
//
#include <hip/hip_runtime.h>
#include <cfloat>

#define HH 64
#define WW 64
#define NKEYS 17
#define CCH 32
#define BG_W 10.0f

struct VI { float v; int i; };
// strict <: keeps left on ties. Call with left = lower index.
__device__ inline VI vimin(VI a, VI b) { return (b.v < a.v) ? b : a; }

__device__ inline VI row4min(const float4& v, int i0) {
    VI a = {v.x, i0}, b = {v.y, i0 + 1}, c = {v.z, i0 + 2}, d = {v.w, i0 + 3};
    return vimin(vimin(a, b), vimin(c, d));
}

__device__ inline void wave_argmin(float &v, int &i) {
    #pragma unroll
    for (int off = 32; off > 0; off >>= 1) {
        float ov = __shfl_down(v, off, 64);
        int   oi = __shfl_down(i, off, 64);
        if (ov < v || (ov == v && oi < i)) { v = ov; i = oi; }
    }
}

__device__ inline unsigned long long packvi(float v, int i) {
    // wdist >= 0 so float bits are monotone: u64 order == (value, index) lex order
    return ((unsigned long long)__float_as_uint(v) << 32) | (unsigned int)i;
}

// Kernel A: one block per (bn, y-stripe). Computes an 18-row wd stripe
// (16 own rows + 1 halo row above/below, recomputed not communicated),
// coarse argmin partial over own rows, 4x upsample of its 64 fine rows,
// fine argmin partial. Partials -> ws[bn*8 + yg] (coarse), [bn*8+4+yg] (fine).
__global__ __launch_bounds__(256) void ee_map(
    const float* __restrict__ kq,      // (B, C, H, W)
    const float* __restrict__ mkeys,   // (B, N, C)
    const int*   __restrict__ mjoints, // (B, N, 2)
    float* __restrict__ out_x4,        // (B, N, 256, 256)
    unsigned long long* __restrict__ ws)
{
    // XCD swizzle at stripe granularity: 4352 blocks = 8 * 544; contiguous
    // 544 stripes = 136 bn = 8 b per XCD -> kq slab (4 MB) fits its L2.
    const int nb  = gridDim.x;
    const int bid = blockIdx.x;
    const int bnyg = ((nb & 7) == 0) ? ((bid & 7) * (nb >> 3) + (bid >> 3)) : bid;
    const int bn  = bnyg >> 2;
    const int yg  = bnyg & 3;
    const int b   = bn / NKEYS;
    const int tid = threadIdx.x;

    __shared__ float s_mk[CCH];
    __shared__ __align__(16) float s_wd[18 * WW];   // rows L=0..17, L=1..16 are own
    __shared__ float s_rv[4];
    __shared__ int   s_ri[4];

    if (tid < CCH) s_mk[tid] = mkeys[bn * CCH + tid];
    __syncthreads();

    float k2 = 0.0f;
    #pragma unroll
    for (int c = 0; c < CCH; c++) { float v = s_mk[c]; k2 += v * v; }

    const int kpx = mjoints[bn * 2 + 0];
    const int kpy = mjoints[bn * 2 + 1];
    const int bxc = (kpx == 0) ? 0 : ((kpx == WW - 1) ? WW - 1 : -1);
    const int byc = (kpy == 0) ? 0 : ((kpy == HH - 1) ? HH - 1 : -1);

    const float4* kq4 = (const float4*)(kq + (size_t)b * CCH * HH * WW);

    VI coarse = {FLT_MAX, 0x7fffffff};
    const int gy_base = yg * 16 - 1;   // gy of LDS row L=0

    // ---- phase 1: 18 rows * 16 float4-chunks = 288 chunks over 256 threads ----
    #pragma unroll
    for (int pass = 0; pass < 2; pass++) {
        const int chunk = tid + (pass << 8);
        if (chunk < 288) {
            const int L  = chunk >> 4;
            const int cx = chunk & 15;
            const int gy = gy_base + L;
            if ((unsigned)gy < (unsigned)HH) {     // OOB halo rows left garbage, never read
                const int gchunk = gy * 16 + cx;
                float4 dot = make_float4(0.f, 0.f, 0.f, 0.f);
                float4 q2  = make_float4(0.f, 0.f, 0.f, 0.f);
                #pragma unroll
                for (int c = 0; c < CCH; c++) {
                    float4 v = kq4[c * 1024 + gchunk];
                    float  m = s_mk[c];
                    dot.x += v.x * m;  dot.y += v.y * m;
                    dot.z += v.z * m;  dot.w += v.w * m;
                    q2.x  += v.x * v.x; q2.y += v.y * v.y;
                    q2.z  += v.z * v.z; q2.w += v.w * v.w;
                }
                float dots[4] = {dot.x, dot.y, dot.z, dot.w};
                float q2s[4]  = {q2.x,  q2.y,  q2.z,  q2.w};
                float4 wd;
                float* wdp = (float*)&wd;
                const int p0 = gy * WW + cx * 4;
                #pragma unroll
                for (int k = 0; k < 4; k++) {
                    const int px = (cx * 4 + k);
                    float d2   = (q2s[k] + k2) - 2.0f * dots[k];
                    float dist = sqrtf(fmaxf(d2, 0.0f));
                    // Closed-form ring weight (Chebyshev ring + border-m=1 special)
                    const int adx = abs(px - kpx);
                    const int ady = abs(gy - kpy);
                    int M = 0;
                    if (adx <= 15 && ady <= adx) M = adx;
                    if (ady <= 15 && adx <= ady) M = max(M, ady);
                    if ((px == bxc && ady <= 1) || (gy == byc && adx <= 1)) M = max(M, 1);
                    float wgt = (M > 0) ? fmaf(0.25f, (float)M, 0.5f) : BG_W;
                    wdp[k] = dist * wgt;
                }
                ((float4*)s_wd)[chunk] = wd;       // LDS float4 idx == chunk
                if (L >= 1 && L <= 16) {           // own rows only
                    coarse = vimin(coarse, row4min(wd, p0));
                }
            }
        }
    }
    __syncthreads();

    // ---- coarse partial reduce -> ws ----
    {
        float cv = coarse.v; int ci = coarse.i;
        wave_argmin(cv, ci);
        if ((tid & 63) == 0) { s_rv[tid >> 6] = cv; s_ri[tid >> 6] = ci; }
    }
    __syncthreads();
    if (tid == 0) {
        float v = s_rv[0]; int i0 = s_ri[0];
        for (int w2 = 1; w2 < 4; w2++) {
            float ov = s_rv[w2]; int oi = s_ri[w2];
            if (ov < v || (ov == v && oi < i0)) { v = ov; i0 = oi; }
        }
        ws[bn * 8 + yg] = packvi(v, i0);
    }

    // ---- phase 2: 4x bilinear upsample of this stripe, float4 stores ----
    // thread = (suby, jx): fine rows [ (16yg+4suby)*4 .. +16 ), fine cols 4jx..4jx+3
    const int jx   = tid & 63;
    const int suby = tid >> 6;
    const int jxm1 = max(jx - 1, 0);
    const int jxp1 = min(jx + 1, WW - 1);
    const bool xe0 = (jx == 0);
    const bool xe1 = (jx == WW - 1);

    auto xrow = [&](int L) -> float4 {
        const float* rr = s_wd + L * WW;
        const float a  = rr[jxm1];
        const float bb = rr[jx];
        const float c  = rr[jxp1];
        float4 o;
        o.x = xe0 ? bb : fmaf(0.375f, a, 0.625f * bb);
        o.y = xe0 ? bb : fmaf(0.125f, a, 0.875f * bb);
        o.z = xe1 ? bb : fmaf(0.125f, c, 0.875f * bb);
        o.w = xe1 ? bb : fmaf(0.375f, c, 0.625f * bb);
        return o;
    };
    auto lerp4 = [](float wa, const float4& A, float wb, const float4& B) {
        float4 o;
        o.x = fmaf(wa, A.x, wb * B.x);
        o.y = fmaf(wa, A.y, wb * B.y);
        o.z = fmaf(wa, A.z, wb * B.z);
        o.w = fmaf(wa, A.w, wb * B.w);
        return o;
    };

    VI fine = {FLT_MAX, 0x7fffffff};
    float4* xo4 = (float4*)(out_x4 + (size_t)bn * (256 * 256)) + jx;

    const int jy0 = yg * 16 + suby * 4;
    const int L0  = suby * 4 + 1;          // LDS row of jy0
    float4 Xc = xrow(L0);
    float4 Xp = xrow(L0 - 1);              // L0-1 >= 0; garbage iff jy0==0 (unused then)

    #pragma unroll
    for (int q = 0; q < 4; q++) {
        const int jy = jy0 + q;
        const int L  = L0 + q;
        const float4 Xn = xrow(L + 1);     // L+1 <= 17; garbage iff jy==63 (unused then)
        float4 v0, v1, v2, v3;
        if (jy == 0) { v0 = Xc; v1 = Xc; }
        else {
            v0 = lerp4(0.375f, Xp, 0.625f, Xc);
            v1 = lerp4(0.125f, Xp, 0.875f, Xc);
        }
        if (jy == HH - 1) { v2 = Xc; v3 = Xc; }
        else {
            v2 = lerp4(0.875f, Xc, 0.125f, Xn);
            v3 = lerp4(0.625f, Xc, 0.375f, Xn);
        }
        const int r0 = jy * 4;
        xo4[(size_t)(r0 + 0) * 64] = v0;
        xo4[(size_t)(r0 + 1) * 64] = v1;
        xo4[(size_t)(r0 + 2) * 64] = v2;
        xo4[(size_t)(r0 + 3) * 64] = v3;
        const int ib = r0 * 256 + 4 * jx;
        VI a0 = row4min(v0, ib);
        VI a1 = row4min(v1, ib + 256);
        VI a2 = row4min(v2, ib + 512);
        VI a3 = row4min(v3, ib + 768);
        fine = vimin(fine, vimin(vimin(a0, a1), vimin(a2, a3)));
        Xp = Xc;
        Xc = Xn;
    }

    // ---- fine partial reduce -> ws ----
    {
        float fv = fine.v; int fi = fine.i;
        wave_argmin(fv, fi);
        __syncthreads();   // s_rv/s_ri reuse
        if ((tid & 63) == 0) { s_rv[tid >> 6] = fv; s_ri[tid >> 6] = fi; }
    }
    __syncthreads();
    if (tid == 0) {
        float v = s_rv[0]; int i0 = s_ri[0];
        for (int w2 = 1; w2 < 4; w2++) {
            float ov = s_rv[w2]; int oi = s_ri[w2];
            if (ov < v || (ov == v && oi < i0)) { v = ov; i0 = oi; }
        }
        ws[bn * 8 + 4 + yg] = packvi(v, i0);
    }
}

// Kernel B: per bn, reduce the 4 stripe partials, emit joints/valid/keys.
__global__ __launch_bounds__(64) void ee_fin(
    const float* __restrict__ kq,
    const float* __restrict__ mkeys,
    float* __restrict__ out_joints,
    float* __restrict__ out_valid,
    float* __restrict__ out_keys,
    const unsigned long long* __restrict__ ws)
{
    const int bn   = blockIdx.x;
    const int b    = bn / NKEYS;
    const int lane = threadIdx.x;

    unsigned long long pc = (lane < 4) ? ws[bn * 8 + lane]     : ~0ull;
    unsigned long long pf = (lane < 4) ? ws[bn * 8 + 4 + lane] : ~0ull;
    #pragma unroll
    for (int off = 1; off <= 2; off <<= 1) {
        unsigned long long o;
        o = __shfl_xor(pc, off, 64); if (o < pc) pc = o;
        o = __shfl_xor(pf, off, 64); if (o < pf) pf = o;
    }
    pc = __shfl(pc, 0, 64);
    pf = __shfl(pf, 0, 64);

    const float min_d = __uint_as_float((unsigned int)(pc >> 32));
    const int   cbest = (int)(pc & 0xffffffffu);

    const float mv = (lane < CCH) ? mkeys[bn * CCH + lane] : 0.0f;
    const bool  nz = __any(mv != 0.0f);
    const bool  valid = nz && ((int)floorf(min_d) <= 5);

    if (lane < CCH) {
        float o = valid ? kq[(size_t)(b * CCH + lane) * (HH * WW) + cbest] : mv;
        out_keys[bn * CCH + lane] = o;
    }
    if (lane == 0) {
        const int fi = (int)(pf & 0xffffffffu);
        out_joints[bn * 2 + 0] = (float)(valid ? (fi >> 8)  : -1);
        out_joints[bn * 2 + 1] = (float)(valid ? (fi & 255) : -1);
        out_valid[bn] = valid ? 1.0f : 0.0f;
    }
}

extern "C" void kernel_launch(void* const* d_in, const int* in_sizes, int n_in,
                              void* d_out, int out_size, void* d_ws, size_t ws_size,
                              hipStream_t stream) {
    const float* kq = (const float*)d_in[0];
    const float* mk = (const float*)d_in[1];
    const int*   mj = (const int*)d_in[2];

    const int B  = in_sizes[1] / (NKEYS * CCH);   // 64
    const int BN = B * NKEYS;                     // 1088

    float* out_f     = (float*)d_out;
    float* o_joints  = out_f;                     // B*N*2
    float* o_valid   = o_joints + BN * 2;         // B*N
    float* o_keys    = o_valid + BN;              // B*N*C
    float* o_x4      = o_keys + BN * CCH;         // B*N*256*256

    // Stripe-argmin partials: BN*8 u64. Prefer d_ws; if undersized, stash in
    // the o_keys region (BN*16 floats <= BN*32 floats) — kernel B reads the
    // partials before overwriting out_keys (single wave, program-ordered).
    unsigned long long* ws;
    if (ws_size >= (size_t)BN * 8 * sizeof(unsigned long long)) {
        ws = (unsigned long long*)d_ws;
    } else {
        ws = (unsigned long long*)o_keys;
    }

    ee_map<<<dim3(BN * 4), dim3(256), 0, stream>>>(kq, mk, mj, o_x4, ws);
    ee_fin<<<dim3(BN), dim3(64), 0, stream>>>(kq, mk, o_joints, o_valid, o_keys, ws);
}